// Round 4
// baseline (675.480 us; speedup 1.0000x reference)
//
#include <hip/hip_runtime.h>
#include <math.h>

#define N_PIX (512 * 512)      // 262144 pixels per tensor-channel
#define NUM_CLASSES 150
#define CF 256                 // feature channels (M)
#define KTILE 64               // pixels per LDS tile
#define CHUNK 2048             // pixels per block (split-K chunk)
#define NTILES (CHUNK / KTILE) // 32
#define NBLK (N_PIX / CHUNK)   // 128 -> grid 128 x 2 tensors = 1 block/CU
#define THREADS 512            // 8 waves; wave w owns channels [32w, 32w+32)
#define EPS 1e-8f

typedef __attribute__((ext_vector_type(8))) short short8;  // 8 bf16 = 4 VGPR
typedef __attribute__((ext_vector_type(4))) float f32x4;   // MFMA acc frag

// ---------------------------------------------------------------------------
// ws layout (floats):
//   [0, 76800)       sums: [2 tensors][150 classes][256 channels]
//   [76800, 77100)   counts: [2 tensors][150 classes]
//
// Round-4: the op IS a GEMM: sums = F[256 x K] * OneHot[K x 150], K = pixels.
// Scatter structure forced 64-line wave-loads (per-thread 1MB-strided
// streams) -> TA/L1 transaction-bound at ~2.4 TB/s. GEMM structure stages
// f32 tiles via global_load_lds (16 lines/wave-op), splits to bf16 hi+lo
// in-register (error ~2^-17 rel), builds one-hot B-frags from labels with
// compares, and runs mfma_f32_16x16x32_bf16. Wave w stages exactly the
// channels it consumes -> per-wave-private double buffer, NO barriers in
// the main loop, counted vmcnt(8) only. A-reads use a 16B-slot XOR swizzle
// (inverse-swizzled GLOBAL source + linear LDS dest + swizzled ds_read) for
// bank-conflict-free ds_read_b128. Counts ride on the B-build compares
// (wave 0 only; exact integers).
// ---------------------------------------------------------------------------

__device__ __forceinline__ unsigned bf16r(float f) {  // f32 -> bf16 bits, RNE
  const unsigned u = __float_as_uint(f);
  return (u + 0x7FFFu + ((u >> 16) & 1u)) >> 16;
}

__device__ __forceinline__ void cvt_hilo(const float4& A, const float4& B,
                                         short8& hi, short8& lo) {
  union { unsigned u[4]; short8 v; } H, L;
  const float ff[8] = {A.x, A.y, A.z, A.w, B.x, B.y, B.z, B.w};
#pragma unroll
  for (int p = 0; p < 4; ++p) {
    const float f0 = ff[2 * p], f1 = ff[2 * p + 1];
    const unsigned h0 = bf16r(f0), h1 = bf16r(f1);
    // hi is exact in f32; residual subtraction is exact (Sterbenz)
    const unsigned r0 = bf16r(f0 - __uint_as_float(h0 << 16));
    const unsigned r1 = bf16r(f1 - __uint_as_float(h1 << 16));
    H.u[p] = h0 | (h1 << 16);
    L.u[p] = r0 | (r1 << 16);
  }
  hi = H.v;
  lo = L.v;
}

// Issue 8 global_load_lds (1 KB each) staging wave w's 32 ch-rows of tile KT.
// LDS dest is linear (base + lane*16); the 16B-slot swizzle is applied by
// permuting the GLOBAL source address (T21: both-sides-or-neither).
#define STAGE(BUF, KT)                                                       \
  {                                                                          \
    _Pragma("unroll") for (int i = 0; i < 8; ++i) {                          \
      const int op = w * 8 + i;                                              \
      const int ch = op * 4 + g;       /* 4 ch-rows (256B) per 1KB op */     \
      const int sg = l15 ^ (ch & 15);  /* inverse-swizzled 16B slot */       \
      const float* gsrc =                                                    \
          f + (size_t)ch * N_PIX + (size_t)(pix0 + (KT) * KTILE + sg * 4);   \
      __builtin_amdgcn_global_load_lds(                                      \
          (const __attribute__((address_space(1))) void*)gsrc,               \
          (__attribute__((address_space(3))) void*)&fls[BUF][op * 256], 16,  \
          0, 0);                                                             \
    }                                                                        \
  }

__global__ __launch_bounds__(THREADS, 2) void center_gemm_kernel(
    const float* __restrict__ f_src, const float* __restrict__ f_trg,
    const int* __restrict__ l_src, const int* __restrict__ l_trg,
    float* __restrict__ sums, float* __restrict__ cnt) {
  const int tensor = blockIdx.z;
  const float* __restrict__ f = tensor ? f_trg : f_src;
  const int* __restrict__ lab = tensor ? l_trg : l_src;

  __shared__ float fls[2][KTILE * CF];  // 2 x 64 KB; [ch][64 pix] 256B rows
  __shared__ unsigned slab[CHUNK / 4];  // 512 packed labels (u8 x 4)

  const int t = threadIdx.x;
  const int w = t >> 6;   // wave 0..7
  const int l = t & 63;
  const int l15 = l & 15;
  const int g = l >> 4;   // lane group 0..3
  const int pix0 = blockIdx.x * CHUNK;

  {  // stage chunk labels once, packed u8x4 (coalesced int4)
    const int4 L = ((const int4*)lab)[pix0 / 4 + t];
    slab[t] = (unsigned)L.x | ((unsigned)L.y << 8) | ((unsigned)L.z << 16) |
              ((unsigned)L.w << 24);
  }
  __syncthreads();  // the ONLY barrier; main loop is per-wave independent

  f32x4 acc[2][10];
#pragma unroll
  for (int a = 0; a < 2; ++a)
#pragma unroll
    for (int n = 0; n < 10; ++n) acc[a][n] = (f32x4)0.f;
  int cntr[10];
#pragma unroll
  for (int n = 0; n < 10; ++n) cntr[n] = 0;

  const int cha = 32 * w + l15;  // ct=0 channel row (A-frag row = lane&15)
  const int chb = cha + 16;      // ct=1

  STAGE(0, 0);
  for (int kt = 0; kt < NTILES; ++kt) {
    const int cb = kt & 1;
    float* __restrict__ fbp = &fls[cb][0];
    if (kt + 1 < NTILES) {
      STAGE(cb ^ 1, kt + 1);
      // 16 outstanding (8 cur + 8 next): wait oldest 8 = current buffer.
      asm volatile("s_waitcnt vmcnt(8)" ::: "memory");
    } else {
      asm volatile("s_waitcnt vmcnt(0)" ::: "memory");
    }
    __builtin_amdgcn_sched_barrier(0);
#pragma unroll
    for (int s = 0; s < 2; ++s) {  // two K=32 MFMA steps per 64-pixel tile
      const int sl0 = (((s * 8) + 2 * g) ^ l15) * 4;      // swizzled slots
      const int sl1 = (((s * 8) + 2 * g + 1) ^ l15) * 4;
      const float4 fa0 = *(const float4*)&fbp[cha * 64 + sl0];
      const float4 fa1 = *(const float4*)&fbp[cha * 64 + sl1];
      const float4 fc0 = *(const float4*)&fbp[chb * 64 + sl0];
      const float4 fc1 = *(const float4*)&fbp[chb * 64 + sl1];
      const uint2 lp = *(const uint2*)&slab[kt * 16 + s * 8 + 2 * g];
      short8 AH, AL, CH, CL;
      cvt_hilo(fa0, fa1, AH, AL);
      cvt_hilo(fc0, fc1, CH, CL);
      const int lb0 = lp.x & 255, lb1 = (lp.x >> 8) & 255,
                lb2 = (lp.x >> 16) & 255, lb3 = (int)(lp.x >> 24);
      const int lb4 = lp.y & 255, lb5 = (lp.y >> 8) & 255,
                lb6 = (lp.y >> 16) & 255, lb7 = (int)(lp.y >> 24);
#pragma unroll
      for (int n = 0; n < 10; ++n) {
        const int cls = n * 16 + l15;  // B-frag col = lane&15
        const int m0 = (lb0 == cls), m1 = (lb1 == cls), m2 = (lb2 == cls),
                  m3 = (lb3 == cls), m4 = (lb4 == cls), m5 = (lb5 == cls),
                  m6 = (lb6 == cls), m7 = (lb7 == cls);
        union { unsigned u[4]; short8 v; } B;
        B.u[0] = (m0 ? 0x3F80u : 0u) | (m1 ? 0x3F800000u : 0u);
        B.u[1] = (m2 ? 0x3F80u : 0u) | (m3 ? 0x3F800000u : 0u);
        B.u[2] = (m4 ? 0x3F80u : 0u) | (m5 ? 0x3F800000u : 0u);
        B.u[3] = (m6 ? 0x3F80u : 0u) | (m7 ? 0x3F800000u : 0u);
        if (w == 0)  // counts: each (k, cls) counted exactly once by wave 0
          cntr[n] += m0 + m1 + m2 + m3 + m4 + m5 + m6 + m7;
        acc[0][n] =
            __builtin_amdgcn_mfma_f32_16x16x32_bf16(AH, B.v, acc[0][n], 0, 0, 0);
        acc[0][n] =
            __builtin_amdgcn_mfma_f32_16x16x32_bf16(AL, B.v, acc[0][n], 0, 0, 0);
        acc[1][n] =
            __builtin_amdgcn_mfma_f32_16x16x32_bf16(CH, B.v, acc[1][n], 0, 0, 0);
        acc[1][n] =
            __builtin_amdgcn_mfma_f32_16x16x32_bf16(CL, B.v, acc[1][n], 0, 0, 0);
      }
    }
  }

  // Epilogue: C/D layout col=lane&15 (cls), row=(lane>>4)*4+reg (ch-local).
  float* __restrict__ out = sums + tensor * (NUM_CLASSES * CF);
#pragma unroll
  for (int ct = 0; ct < 2; ++ct) {
    const int ch = 32 * w + ct * 16 + g * 4;
#pragma unroll
    for (int n = 0; n < 10; ++n) {
      const int cls = n * 16 + l15;
      if (cls < NUM_CLASSES) {
        unsafeAtomicAdd(&out[cls * CF + ch + 0], acc[ct][n][0]);
        unsafeAtomicAdd(&out[cls * CF + ch + 1], acc[ct][n][1]);
        unsafeAtomicAdd(&out[cls * CF + ch + 2], acc[ct][n][2]);
        unsafeAtomicAdd(&out[cls * CF + ch + 3], acc[ct][n][3]);
      }
    }
  }
  if (w == 0) {
#pragma unroll
    for (int n = 0; n < 10; ++n) {
      int v = cntr[n];
      v += __shfl_xor(v, 16, 64);  // combine lane groups g
      v += __shfl_xor(v, 32, 64);
      const int cls = n * 16 + l15;
      if (l < 16 && cls < NUM_CLASSES)
        unsafeAtomicAdd(&cnt[tensor * NUM_CLASSES + cls], (float)v);
    }
  }
}

#define FTHREADS 1024
__global__ __launch_bounds__(FTHREADS) void finalize_kernel(
    const float* __restrict__ sums, const float* __restrict__ cnt,
    float* __restrict__ out) {
  const float* ss = sums;
  const float* st = sums + NUM_CLASSES * CF;
  const float* cs = cnt;
  const float* ct = cnt + NUM_CLASSES;
  float acc = 0.f;
  for (int i = threadIdx.x; i < NUM_CLASSES * CF; i += FTHREADS) {
    const int cls = i >> 8;  // CF == 256
    const float d = ss[i] / (cs[cls] + EPS) - st[i] / (ct[cls] + EPS);
    acc += d * d;
  }
#pragma unroll
  for (int off = 32; off > 0; off >>= 1) acc += __shfl_down(acc, off, 64);
  __shared__ float red[FTHREADS / 64];
  const int lane = threadIdx.x & 63;
  const int wid = threadIdx.x >> 6;
  if (lane == 0) red[wid] = acc;
  __syncthreads();
  if (threadIdx.x == 0) {
    float tsum = 0.f;
#pragma unroll
    for (int w = 0; w < FTHREADS / 64; ++w) tsum += red[w];
    out[0] = sqrtf(tsum);
  }
}

extern "C" void kernel_launch(void* const* d_in, const int* in_sizes, int n_in,
                              void* d_out, int out_size, void* d_ws,
                              size_t ws_size, hipStream_t stream) {
  const float* f_src = (const float*)d_in[0];
  const float* f_trg = (const float*)d_in[1];
  const int* l_src = (const int*)d_in[2];
  const int* l_trg = (const int*)d_in[3];
  float* out = (float*)d_out;

  float* sums = (float*)d_ws;                // 2 * 150 * 256 floats
  float* cnt = sums + 2 * NUM_CLASSES * CF;  // 2 * 150 floats

  const size_t zero_bytes =
      (size_t)(2 * NUM_CLASSES * CF + 2 * NUM_CLASSES) * sizeof(float);
  hipMemsetAsync(d_ws, 0, zero_bytes, stream);

  hipLaunchKernelGGL(center_gemm_kernel, dim3(NBLK, 1, 2), dim3(THREADS), 0,
                     stream, f_src, f_trg, l_src, l_trg, sums, cnt);
  hipLaunchKernelGGL(finalize_kernel, dim3(1), dim3(FTHREADS), 0, stream, sums,
                     cnt, out);
}